// Round 2
// baseline (245.424 us; speedup 1.0000x reference)
//
#include <hip/hip_runtime.h>

// CortexNetwork: aff + 0.9*exc - 0.9*inh, relu, broadcast over C.
// R2: 101us, per-CU miss-concurrency limited on single-use data.
// R3: nontemporal weight loads -> phase1 < 61us (below harness fills in profile).
// R4: up-front lateral loads + partials aliased into out (d_ws untouched).
//     dur 247.2 -> 243.8. Top-5 = harness 430MB poison fills @ 86% HBM peak.
// R5 (this round): single up-front load burst (lateral c1 + c2 + affW + x)
//     before ANY arithmetic, and lateral chunk-2 moved from threads t<68
//     (waves 0-1, which also carry all afferent work) to t>=188 (waves 2-3,
//     previously near-idle). Balances ~12 f4-loads/thread across all 4 waves
//     and maximizes per-wave outstanding NT misses.
//     Compulsory traffic: 263 MB -> 38-42us floor at fill-observed 6.9 TB/s.
//     If dur_us doesn't move beyond noise, phase1 is at its BW floor and the
//     remaining 185us of the timed window is harness fill/restore traffic.

constexpr int C   = 16;
constexpr int GX  = 36;
constexpr int GY  = 36;
constexpr int RF  = 24;
constexpr int IMG = 64;
constexpr int GG  = GX * GY;   // 1296
constexpr int RR  = RF * RF;   // 576
constexpr int RR4 = RR / 4;    // 144
constexpr int GG4 = GG / 4;    // 324
constexpr int RFQ = RF / 4;    // 6
constexpr int SPLIT = 4;
constexpr int CPB   = C / SPLIT;   // 4 channels per block

typedef float f4 __attribute__((ext_vector_type(4)));

__global__ __launch_bounds__(256)
void cortex_phase1(const float* __restrict__ x,
                   const float* __restrict__ prev,
                   const float* __restrict__ affW,
                   const float* __restrict__ exW,
                   const float* __restrict__ inW,
                   const int*   __restrict__ rx,
                   const int*   __restrict__ ry,
                   float* __restrict__ partial)
{
    const int bid   = blockIdx.x;
    const int ij    = bid % GG;
    const int split = bid / GG;
    const int cs    = split * CPB;
    const int i = ij / GY;
    const int j = ij - i * GY;
    const int t = threadIdx.x;

    const int rxi = rx[i];
    const int ryj = ry[j];

    // Lateral chunk-2: indices 256..323 handled by threads 188..255
    // (waves 2-3), NOT by t<68 (waves 0-1 carry the afferent work).
    const int  t2 = t + 68;            // in [68,324) for all t -> addr-safe,
    const bool v2 = (t >= 188);        // but only t>=188 may LOAD (NT refetch
                                       // of chunk-1 lines would cost real HBM)
    const f4 fz = {0.0f, 0.0f, 0.0f, 0.0f};

    // ================= single load burst: everything in flight =============
    f4 e0[CPB], h0[CPB], e1[CPB], h1[CPB];
    #pragma unroll
    for (int cc = 0; cc < CPB; ++cc) {
        const size_t base = ((size_t)(cs + cc) * GG + ij) * GG;
        e0[cc] = __builtin_nontemporal_load((const f4*)(exW + base) + t);
        h0[cc] = __builtin_nontemporal_load((const f4*)(inW + base) + t);
    }
    #pragma unroll
    for (int cc = 0; cc < CPB; ++cc) {
        const size_t base = ((size_t)(cs + cc) * GG + ij) * GG;
        if (v2) {
            e1[cc] = __builtin_nontemporal_load((const f4*)(exW + base) + t2);
            h1[cc] = __builtin_nontemporal_load((const f4*)(inW + base) + t2);
        } else {
            e1[cc] = fz;
            h1[cc] = fz;
        }
    }

    const bool va = (t < RR4);
    int u = 0, v0 = 0;
    f4 w[CPB];
    float xv[CPB][4];
    if (va) {
        u  = t / RFQ;
        v0 = 4 * (t - u * RFQ);
        #pragma unroll
        for (int cc = 0; cc < CPB; ++cc) {
            const int c = cs + cc;
            w[cc] = __builtin_nontemporal_load(
                (const f4*)(affW + ((size_t)c * GG + ij) * RR) + t);
        }
        #pragma unroll
        for (int cc = 0; cc < CPB; ++cc) {
            const int c = cs + cc;
            const float* xp = x + ((c * IMG + rxi + u) * IMG + ryj + v0);
            xv[cc][0] = xp[0];
            xv[cc][1] = xp[1];
            xv[cc][2] = xp[2];
            xv[cc][3] = xp[3];
        }
    }

    // ======================= arithmetic ====================================
    float acc = 0.0f;
    if (va) {
        #pragma unroll
        for (int cc = 0; cc < CPB; ++cc) {
            acc = fmaf(w[cc].x, xv[cc][0], acc);
            acc = fmaf(w[cc].y, xv[cc][1], acc);
            acc = fmaf(w[cc].z, xv[cc][2], acc);
            acc = fmaf(w[cc].w, xv[cc][3], acc);
        }
    }

    float lat = 0.0f;
    #pragma unroll
    for (int cc = 0; cc < CPB; ++cc) {
        const float d = (e0[cc].x + e0[cc].y + e0[cc].z + e0[cc].w)
                      + (e1[cc].x + e1[cc].y + e1[cc].z + e1[cc].w)
                      - (h0[cc].x + h0[cc].y + h0[cc].z + h0[cc].w)
                      - (h1[cc].x + h1[cc].y + h1[cc].z + h1[cc].w);
        lat = fmaf(prev[(cs + cc) * GG + ij], d, lat);
    }
    acc = fmaf(0.9f, lat, acc);

    // ---- Block reduction ----
    for (int off = 32; off > 0; off >>= 1)
        acc += __shfl_down(acc, off, 64);

    __shared__ float sred[4];
    const int wave = t >> 6;
    const int lane = t & 63;
    if (lane == 0) sred[wave] = acc;
    __syncthreads();
    if (t == 0)
        partial[split * GG + ij] = sred[0] + sred[1] + sred[2] + sred[3];
}

__global__ __launch_bounds__(256)
void cortex_phase2(const float* __restrict__ partial, float* __restrict__ out)
{
    const int ij = blockIdx.x * blockDim.x + threadIdx.x;
    if (ij < GG) {
        // partial aliases out[0..4*GG): read all 4 partials for this column
        // BEFORE writing any output (per-thread columns are disjoint).
        const float tot = partial[ij] + partial[GG + ij]
                        + partial[2 * GG + ij] + partial[3 * GG + ij];
        const float a = fmaxf(tot, 0.0f);
        #pragma unroll
        for (int c = 0; c < C; ++c)
            out[c * GG + ij] = a;
    }
}

extern "C" void kernel_launch(void* const* d_in, const int* in_sizes, int n_in,
                              void* d_out, int out_size, void* d_ws, size_t ws_size,
                              hipStream_t stream) {
    const float* x     = (const float*)d_in[0];
    const float* prev  = (const float*)d_in[1];
    const float* affW  = (const float*)d_in[2];
    const float* exW   = (const float*)d_in[3];
    const float* inW   = (const float*)d_in[4];
    const int*   rx    = (const int*)d_in[5];
    const int*   ry    = (const int*)d_in[6];
    float* out     = (float*)d_out;
    // Partials live in the first SPLIT*GG floats of out itself; d_ws unused.
    float* partial = out;

    cortex_phase1<<<GG * SPLIT, 256, 0, stream>>>(x, prev, affW, exW, inW, rx, ry, partial);
    cortex_phase2<<<(GG + 255) / 256, 256, 0, stream>>>(partial, out);
}